// Round 10
// baseline (633.121 us; speedup 1.0000x reference)
//
#include <hip/hip_runtime.h>
#include <cmath>

#define TT   6
#define NB   128
#define DIM  192
#define SCALE 0.17677669529663687f

typedef __attribute__((ext_vector_type(8))) short v8s;
typedef __attribute__((ext_vector_type(4))) float v4f;

__device__ __forceinline__ short f2bf(float f) {
  union { float f; unsigned u; } v; v.f = f;
  unsigned r = v.u + 0x7fffu + ((v.u >> 16) & 1u);
  return (short)(r >> 16);
}

// ---- fused prep: bf16 weight conversion + sine position table, one launch ----
__global__ void prep_kernel(const float* __restrict__ Wqkv, const float* __restrict__ Wproj,
                            const float* __restrict__ W1, const float* __restrict__ W2,
                            short* __restrict__ dWqkv, short* __restrict__ dWproj,
                            short* __restrict__ dW1, short* __restrict__ dW2,
                            float* __restrict__ pos) {
  int idx = blockIdx.x * 256 + threadIdx.x;
  const float* src = nullptr; short* dst = nullptr; int off = 0;
  if (idx < 27648)      { src = Wqkv;  dst = dWqkv;  off = idx; }
  else if (idx < 46080) { src = Wproj; dst = dWproj; off = idx - 27648; }
  else if (idx < 55296) { src = W1;    dst = dW1;    off = idx - 46080; }
  else if (idx < 64512) { src = W2;    dst = dW2;    off = idx - 55296; }
  else if (idx < 67584) {
    int p0 = (idx - 64512) * 4;
    float4 r;
    float* rp = (float*)&r;
#pragma unroll
    for (int jj = 0; jj < 4; jj++) {
      int p = p0 + jj;
      int row = p / 192, c = p - row * 192;
      int e  = (c < 96) ? (row >> 3) : (row & 7);
      int cc = (c < 96) ? c : c - 96;
      int m = cc >> 1;
      float embed = (float)(e + 1) * (6.283185307179586f / 8.000001f);
      float dt = powf(10000.0f, (float)m * (1.0f / 48.0f));
      float ang = embed / dt;
      rp[jj] = (cc & 1) ? cosf(ang) : sinf(ang);
    }
    *(float4*)(pos + p0) = r;
    return;
  } else return;
  const float* s = src + off * 4;
  short4 r;
  r.x = f2bf(s[0]); r.y = f2bf(s[1]); r.z = f2bf(s[2]); r.w = f2bf(s[3]);
  *(short4*)(dst + off * 4) = r;
}

// ---- QKV pre-kernel: one block per (b,t). Q,K row-major [hw][ch]; V transposed [ch][hw].
// Grid swizzled with the SAME XCD mapping as fused_all (r4-verified: FETCH 186->78MB).
__global__ __launch_bounds__(256) void qkv_kernel(
    const float* __restrict__ x, const float* __restrict__ pos,
    const short* __restrict__ Wqkv_bf,
    short* __restrict__ Qb, short* __restrict__ Kb, short* __restrict__ Vtb) {
  __shared__ short XP[64 * 200];
  int bid = blockIdx.x;
  int xcd = bid & 7, idx = bid >> 3;   // 96 blocks per XCD
  int bq = idx / TT;
  int b = xcd * 16 + bq, t = idx - bq * TT;
  int tid = threadIdx.x, w = tid >> 6, lane = tid & 63;
  int l15 = lane & 15, quad = lane >> 4;
  const float* xrow = x + (size_t)(b * (TT * 64) + t * 64) * DIM;
  for (int c = tid; c < 64 * 24; c += 256) {
    int row = c / 24, col8 = (c - (c / 24) * 24) * 8;
    const float* xs = xrow + row * DIM + col8;
    const float* pp = pos + row * DIM + col8;
    v8s r8;
#pragma unroll
    for (int jj = 0; jj < 8; jj++) r8[jj] = f2bf(xs[jj] + pp[jj]);
    *(v8s*)(XP + row * 200 + col8) = r8;
  }
  __syncthreads();
  const v4f vzero = {0.f, 0.f, 0.f, 0.f};
  size_t obase = (size_t)(b * TT + t) * 64 * DIM;
#pragma unroll
  for (int cti = 0; cti < 9; cti++) {
    int r0 = w * 144 + cti * 16;
    v4f acc[4] = {vzero, vzero, vzero, vzero};
#pragma unroll
    for (int ks = 0; ks < 6; ks++) {
      v8s a = *(const v8s*)(Wqkv_bf + (size_t)(r0 + l15) * 192 + ks * 32 + quad * 8);
#pragma unroll
      for (int nt = 0; nt < 4; nt++) {
        v8s bb = *(const v8s*)(XP + (nt * 16 + l15) * 200 + ks * 32 + quad * 8);
        acc[nt] = __builtin_amdgcn_mfma_f32_16x16x32_bf16(a, bb, acc[nt], 0, 0, 0);
      }
    }
    int R = r0 + quad * 4;
#pragma unroll
    for (int nt = 0; nt < 4; nt++) {
      int hw = nt * 16 + l15;
      if (R < 192) {
        short4 s;
        s.x = f2bf(acc[nt][0] * SCALE); s.y = f2bf(acc[nt][1] * SCALE);
        s.z = f2bf(acc[nt][2] * SCALE); s.w = f2bf(acc[nt][3] * SCALE);
        *(short4*)(Qb + obase + (size_t)hw * 192 + R) = s;
      } else if (R < 384) {
        short4 s;
        s.x = f2bf(acc[nt][0]); s.y = f2bf(acc[nt][1]);
        s.z = f2bf(acc[nt][2]); s.w = f2bf(acc[nt][3]);
        *(short4*)(Kb + obase + (size_t)hw * 192 + (R - 192)) = s;
      } else {
#pragma unroll
        for (int r = 0; r < 4; r++)
          Vtb[obase + (size_t)(R - 384 + r) * 64 + hw] = f2bf(acc[nt][r]);
      }
    }
  }
}

// register P-transpose (r4/r9-verified spill-free): S[4]*inv -> PV B fragments
__device__ __forceinline__ void ptrans(const v4f S[4], float inv,
                                       int srcA, int srcB, bool hiq,
                                       v8s& B0v, v8s& B1v) {
  unsigned pk00, pk01, pk10, pk11, pk20, pk21, pk30, pk31;
  {
    float a0 = S[0][0] * inv, a1 = S[0][1] * inv, a2 = S[0][2] * inv, a3 = S[0][3] * inv;
    __asm__("v_cvt_pk_bf16_f32 %0, %1, %2" : "=v"(pk00) : "v"(a0), "v"(a1));
    __asm__("v_cvt_pk_bf16_f32 %0, %1, %2" : "=v"(pk01) : "v"(a2), "v"(a3));
    float b0 = S[1][0] * inv, b1_ = S[1][1] * inv, b2_ = S[1][2] * inv, b3 = S[1][3] * inv;
    __asm__("v_cvt_pk_bf16_f32 %0, %1, %2" : "=v"(pk10) : "v"(b0), "v"(b1_));
    __asm__("v_cvt_pk_bf16_f32 %0, %1, %2" : "=v"(pk11) : "v"(b2_), "v"(b3));
    float c0 = S[2][0] * inv, c1 = S[2][1] * inv, c2 = S[2][2] * inv, c3 = S[2][3] * inv;
    __asm__("v_cvt_pk_bf16_f32 %0, %1, %2" : "=v"(pk20) : "v"(c0), "v"(c1));
    __asm__("v_cvt_pk_bf16_f32 %0, %1, %2" : "=v"(pk21) : "v"(c2), "v"(c3));
    float d0 = S[3][0] * inv, d1 = S[3][1] * inv, d2 = S[3][2] * inv, d3 = S[3][3] * inv;
    __asm__("v_cvt_pk_bf16_f32 %0, %1, %2" : "=v"(pk30) : "v"(d0), "v"(d1));
    __asm__("v_cvt_pk_bf16_f32 %0, %1, %2" : "=v"(pk31) : "v"(d2), "v"(d3));
  }
  union { unsigned u[4]; v8s v; } B0, B1;
  unsigned ta, tb;
  ta = (unsigned)__shfl((int)pk00, srcA); tb = (unsigned)__shfl((int)pk10, srcA);
  B0.u[0] = hiq ? tb : ta;
  ta = (unsigned)__shfl((int)pk01, srcA); tb = (unsigned)__shfl((int)pk11, srcA);
  B0.u[1] = hiq ? tb : ta;
  ta = (unsigned)__shfl((int)pk00, srcB); tb = (unsigned)__shfl((int)pk10, srcB);
  B0.u[2] = hiq ? tb : ta;
  ta = (unsigned)__shfl((int)pk01, srcB); tb = (unsigned)__shfl((int)pk11, srcB);
  B0.u[3] = hiq ? tb : ta;
  ta = (unsigned)__shfl((int)pk20, srcA); tb = (unsigned)__shfl((int)pk30, srcA);
  B1.u[0] = hiq ? tb : ta;
  ta = (unsigned)__shfl((int)pk21, srcA); tb = (unsigned)__shfl((int)pk31, srcA);
  B1.u[1] = hiq ? tb : ta;
  ta = (unsigned)__shfl((int)pk20, srcB); tb = (unsigned)__shfl((int)pk30, srcB);
  B1.u[2] = hiq ? tb : ta;
  ta = (unsigned)__shfl((int)pk21, srcB); tb = (unsigned)__shfl((int)pk31, srcB);
  B1.u[3] = hiq ? tb : ta;
  B0v = B0.v; B1v = B1.v;
}

// ---- main fused kernel: one block per (i,b,half), 256 threads (4 waves), 32 hw rows.
// r9 structure with the j-loop unrolled 2x: every phase processes j and j+1 together.
// The j-iterations are independent (they meet only at the associative acc+=), so each
// phase gets two independent dependency chains per wave (double MLP/ILP) and each
// weight fragment is loaded once and used 4x (2 nt x 2 j). Barriers 5/j -> 2.5/j.
// This attacks the measured profile (r1/r8/r9 all ~460us, all pipes <21%, waves
// individually stalled ~85% on serial load->use chains).
__global__ __launch_bounds__(256, 4) void fused_all(
    const float* __restrict__ x,
    const short* __restrict__ Qb, const short* __restrict__ Kb,
    const short* __restrict__ Vtb,
    const short* __restrict__ Wproj_bf, const short* __restrict__ W1_bf,
    const short* __restrict__ W2_bf,
    const float* __restrict__ bproj, const float* __restrict__ gamma,
    const float* __restrict__ beta, const float* __restrict__ b1,
    const float* __restrict__ b2,
    float* __restrict__ out) {
  __shared__ short SPa[32 * 200];    // Xi staging / o_a / y1n_a; f32 acc staging in epilogue
  __shared__ short SPb[32 * 200];    // o_b / y1n_b
  __shared__ short HBa[32 * 200];    // gelu h_a
  __shared__ short HBb[32 * 200];    // gelu h_b
  __shared__ float LNp[2][32][4][2]; // LN partials per j-slot: [jj][row][wc][s1,s2]

  // XCD swizzle: 12 blocks (6 i x 2 half) sharing b land on one XCD
  int bid = blockIdx.x;
  int xcd = bid & 7, idx = bid >> 3;     // 192 per XCD
  int bq = idx / 12;
  int rem = idx - bq * 12;
  int i = rem >> 1, half = rem & 1;
  int b = xcd * 16 + bq;

  int tid = threadIdx.x, w = tid >> 6, lane = tid & 63;
  int l15 = lane & 15, quad = lane >> 4;
  int wc = w;                        // GEMM channel slice
  int qt = w & 1, hg = w >> 1;       // attention: q-tile, head-group
  int cb = wc * 48;
  const v4f vzero = {0.f, 0.f, 0.f, 0.f};

  // ---- stage Xi (x.view rows, this half) as bf16 into SPa ----
  const float* xi = x + (size_t)((i * NB + b) * 64 + half * 32) * DIM;
  for (int c = tid; c < 32 * 24; c += 256) {
    int row = c / 24, col8 = (c - (c / 24) * 24) * 8;
    const float* xs = xi + row * DIM + col8;
    v8s r8;
#pragma unroll
    for (int jj = 0; jj < 8; jj++) r8[jj] = f2bf(xs[jj]);
    *(v8s*)(SPa + row * 200 + col8) = r8;
  }

  // ---- hoist Q fragments (j-invariant): wave's 16 q-rows x its 3 heads ----
  const short* Qi = Qb + (size_t)(b * TT + i) * 64 * DIM;
  v8s qa[3];
#pragma unroll
  for (int hh = 0; hh < 3; hh++)
    qa[hh] = *(const v8s*)(Qi + (size_t)(half * 32 + qt * 16 + l15) * 192 + (hg * 3 + hh) * 32 + quad * 8);

  v4f acc[3][2];
#pragma unroll
  for (int cti = 0; cti < 3; cti++)
#pragma unroll
    for (int nt = 0; nt < 2; nt++) acc[cti][nt] = vzero;

  __syncthreads();                   // Xi staged

  // ---- y1x = Wproj[:,192:384] . Xi^T (j-invariant, registers) ----
  v4f y1x[3][2];
#pragma unroll
  for (int cti = 0; cti < 3; cti++)
#pragma unroll
    for (int nt = 0; nt < 2; nt++) y1x[cti][nt] = vzero;
#pragma unroll
  for (int ks = 0; ks < 6; ks++) {
    v8s bxi[2];
#pragma unroll
    for (int nt = 0; nt < 2; nt++)
      bxi[nt] = *(const v8s*)(SPa + (nt * 16 + l15) * 200 + ks * 32 + quad * 8);
#pragma unroll
    for (int cti = 0; cti < 3; cti++) {
      v8s a = *(const v8s*)(Wproj_bf + (size_t)(cb + cti * 16 + l15) * 384 + 192 + ks * 32 + quad * 8);
#pragma unroll
      for (int nt = 0; nt < 2; nt++)
        y1x[cti][nt] = __builtin_amdgcn_mfma_f32_16x16x32_bf16(a, bxi[nt], y1x[cti][nt], 0, 0, 0);
    }
  }

  int srcA = l15 + ((lane & 16) << 1);   // l15 + 32*(quad&1)
  int srcB = srcA + 16;
  bool hiq = (lane & 32) != 0;           // quad >= 2

  for (int j = 0; j < TT; j += 2) {
    __syncthreads();               // A: SPa/SPb free (prior G2 reads done; j=0: y1x reads done)
    {
      const short* Kja = Kb + (size_t)(b * TT + j) * 64 * DIM;
      const short* Vja = Vtb + (size_t)(b * TT + j) * 64 * DIM;
      const short* Kjb = Kja + 64 * DIM;
      const short* Vjb = Vja + 64 * DIM;
#pragma unroll
      for (int hh = 0; hh < 3; hh++) {
        int h = hg * 3 + hh;
        // two independent QK^T chains
        v4f Sa[4], Sb[4];
#pragma unroll
        for (int cta = 0; cta < 4; cta++) {
          v8s ka = *(const v8s*)(Kja + (size_t)(cta * 16 + l15) * 192 + h * 32 + quad * 8);
          Sa[cta] = __builtin_amdgcn_mfma_f32_16x16x32_bf16(ka, qa[hh], vzero, 0, 0, 0);
        }
#pragma unroll
        for (int cta = 0; cta < 4; cta++) {
          v8s kb = *(const v8s*)(Kjb + (size_t)(cta * 16 + l15) * 192 + h * 32 + quad * 8);
          Sb[cta] = __builtin_amdgcn_mfma_f32_16x16x32_bf16(kb, qa[hh], vzero, 0, 0, 0);
        }
        // two softmax chains (independent; scheduler interleaves)
        float mxa = -1e30f, mxb = -1e30f;
#pragma unroll
        for (int cta = 0; cta < 4; cta++)
#pragma unroll
          for (int r = 0; r < 4; r++) { mxa = fmaxf(mxa, Sa[cta][r]); mxb = fmaxf(mxb, Sb[cta][r]); }
        mxa = fmaxf(mxa, __shfl_xor(mxa, 16, 64)); mxb = fmaxf(mxb, __shfl_xor(mxb, 16, 64));
        mxa = fmaxf(mxa, __shfl_xor(mxa, 32, 64)); mxb = fmaxf(mxb, __shfl_xor(mxb, 32, 64));
        float suma = 0.f, sumb = 0.f;
#pragma unroll
        for (int cta = 0; cta < 4; cta++)
#pragma unroll
          for (int r = 0; r < 4; r++) {
            float ea = __expf(Sa[cta][r] - mxa); Sa[cta][r] = ea; suma += ea;
            float eb = __expf(Sb[cta][r] - mxb); Sb[cta][r] = eb; sumb += eb;
          }
        suma += __shfl_xor(suma, 16, 64); sumb += __shfl_xor(sumb, 16, 64);
        suma += __shfl_xor(suma, 32, 64); sumb += __shfl_xor(sumb, 32, 64);
        float inva = 1.0f / suma, invb = 1.0f / sumb;
        v8s B0a, B1a, B0b, B1b;
        ptrans(Sa, inva, srcA, srcB, hiq, B0a, B1a);
        ptrans(Sb, invb, srcA, srcB, hiq, B0b, B1b);
        // PV for both j's
#pragma unroll
        for (int ct2 = 0; ct2 < 2; ct2++) {
          v8s av0a = *(const v8s*)(Vja + (size_t)(h * 32 + ct2 * 16 + l15) * 64 + quad * 8);
          v8s av1a = *(const v8s*)(Vja + (size_t)(h * 32 + ct2 * 16 + l15) * 64 + 32 + quad * 8);
          v4f oa = __builtin_amdgcn_mfma_f32_16x16x32_bf16(av0a, B0a, vzero, 0, 0, 0);
          oa = __builtin_amdgcn_mfma_f32_16x16x32_bf16(av1a, B1a, oa, 0, 0, 0);
          short4 sa;
          sa.x = f2bf(oa[0]); sa.y = f2bf(oa[1]); sa.z = f2bf(oa[2]); sa.w = f2bf(oa[3]);
          *(short4*)(&SPa[(qt * 16 + l15) * 200 + h * 32 + ct2 * 16 + quad * 4]) = sa;
          v8s av0b = *(const v8s*)(Vjb + (size_t)(h * 32 + ct2 * 16 + l15) * 64 + quad * 8);
          v8s av1b = *(const v8s*)(Vjb + (size_t)(h * 32 + ct2 * 16 + l15) * 64 + 32 + quad * 8);
          v4f ob = __builtin_amdgcn_mfma_f32_16x16x32_bf16(av0b, B0b, vzero, 0, 0, 0);
          ob = __builtin_amdgcn_mfma_f32_16x16x32_bf16(av1b, B1b, ob, 0, 0, 0);
          short4 sb;
          sb.x = f2bf(ob[0]); sb.y = f2bf(ob[1]); sb.z = f2bf(ob[2]); sb.w = f2bf(ob[3]);
          *(short4*)(&SPb[(qt * 16 + l15) * 200 + h * 32 + ct2 * 16 + quad * 4]) = sb;
        }
      }
    }
    __syncthreads();               // B: o_a, o_b ready

    // ---- G1 for both j's: one weight load -> 4 MFMAs ----
    v4f y1a[3][2], y1b[3][2];
#pragma unroll
    for (int cti = 0; cti < 3; cti++)
#pragma unroll
      for (int nt = 0; nt < 2; nt++) { y1a[cti][nt] = y1x[cti][nt]; y1b[cti][nt] = y1x[cti][nt]; }
#pragma unroll
    for (int ks = 0; ks < 6; ks++) {
      v8s boa[2], bob[2];
#pragma unroll
      for (int nt = 0; nt < 2; nt++) {
        boa[nt] = *(const v8s*)(SPa + (nt * 16 + l15) * 200 + ks * 32 + quad * 8);
        bob[nt] = *(const v8s*)(SPb + (nt * 16 + l15) * 200 + ks * 32 + quad * 8);
      }
#pragma unroll
      for (int cti = 0; cti < 3; cti++) {
        v8s a = *(const v8s*)(Wproj_bf + (size_t)(cb + cti * 16 + l15) * 384 + ks * 32 + quad * 8);
#pragma unroll
        for (int nt = 0; nt < 2; nt++) {
          y1a[cti][nt] = __builtin_amdgcn_mfma_f32_16x16x32_bf16(a, boa[nt], y1a[cti][nt], 0, 0, 0);
          y1b[cti][nt] = __builtin_amdgcn_mfma_f32_16x16x32_bf16(a, bob[nt], y1b[cti][nt], 0, 0, 0);
        }
      }
    }
#pragma unroll
    for (int cti = 0; cti < 3; cti++) {
      float4 bp4 = *(const float4*)(bproj + cb + cti * 16 + quad * 4);
#pragma unroll
      for (int nt = 0; nt < 2; nt++) {
        y1a[cti][nt][0] += bp4.x; y1a[cti][nt][1] += bp4.y;
        y1a[cti][nt][2] += bp4.z; y1a[cti][nt][3] += bp4.w;
        y1b[cti][nt][0] += bp4.x; y1b[cti][nt][1] += bp4.y;
        y1b[cti][nt][2] += bp4.z; y1b[cti][nt][3] += bp4.w;
      }
    }
#pragma unroll
    for (int nt = 0; nt < 2; nt++) {
      float s1a = 0.f, s2a = 0.f, s1b = 0.f, s2b = 0.f;
#pragma unroll
      for (int cti = 0; cti < 3; cti++)
#pragma unroll
        for (int r = 0; r < 4; r++) {
          float va = y1a[cti][nt][r]; s1a += va; s2a += va * va;
          float vb = y1b[cti][nt][r]; s1b += vb; s2b += vb * vb;
        }
      s1a += __shfl_xor(s1a, 16, 64); s2a += __shfl_xor(s2a, 16, 64);
      s1a += __shfl_xor(s1a, 32, 64); s2a += __shfl_xor(s2a, 32, 64);
      s1b += __shfl_xor(s1b, 16, 64); s2b += __shfl_xor(s2b, 16, 64);
      s1b += __shfl_xor(s1b, 32, 64); s2b += __shfl_xor(s2b, 32, 64);
      if (quad == 0) {
        LNp[0][nt * 16 + l15][wc][0] = s1a; LNp[0][nt * 16 + l15][wc][1] = s2a;
        LNp[1][nt * 16 + l15][wc][0] = s1b; LNp[1][nt * 16 + l15][wc][1] = s2b;
      }
    }
    __syncthreads();               // C: partials visible; G1 SP reads done
    float mua[2], rsa[2], mub[2], rsb[2];
#pragma unroll
    for (int nt = 0; nt < 2; nt++) {
      int row = nt * 16 + l15;
      float s1a = 0.f, s2a = 0.f, s1b = 0.f, s2b = 0.f;
#pragma unroll
      for (int ww = 0; ww < 4; ww++) {
        s1a += LNp[0][row][ww][0]; s2a += LNp[0][row][ww][1];
        s1b += LNp[1][row][ww][0]; s2b += LNp[1][row][ww][1];
      }
      float ma = s1a * (1.0f / 192.0f), mb = s1b * (1.0f / 192.0f);
      mua[nt] = ma; rsa[nt] = rsqrtf(s2a * (1.0f / 192.0f) - ma * ma + 1e-5f);
      mub[nt] = mb; rsb[nt] = rsqrtf(s2b * (1.0f / 192.0f) - mb * mb + 1e-5f);
    }
#pragma unroll
    for (int cti = 0; cti < 3; cti++) {
      float4 g4 = *(const float4*)(gamma + cb + cti * 16 + quad * 4);
      float4 be4 = *(const float4*)(beta + cb + cti * 16 + quad * 4);
#pragma unroll
      for (int nt = 0; nt < 2; nt++) {
        short4 sa, sb;
        sa.x = f2bf((y1a[cti][nt][0] - mua[nt]) * rsa[nt] * g4.x + be4.x);
        sa.y = f2bf((y1a[cti][nt][1] - mua[nt]) * rsa[nt] * g4.y + be4.y);
        sa.z = f2bf((y1a[cti][nt][2] - mua[nt]) * rsa[nt] * g4.z + be4.z);
        sa.w = f2bf((y1a[cti][nt][3] - mua[nt]) * rsa[nt] * g4.w + be4.w);
        *(short4*)(&SPa[(nt * 16 + l15) * 200 + cb + cti * 16 + quad * 4]) = sa;
        sb.x = f2bf((y1b[cti][nt][0] - mub[nt]) * rsb[nt] * g4.x + be4.x);
        sb.y = f2bf((y1b[cti][nt][1] - mub[nt]) * rsb[nt] * g4.y + be4.y);
        sb.z = f2bf((y1b[cti][nt][2] - mub[nt]) * rsb[nt] * g4.z + be4.z);
        sb.w = f2bf((y1b[cti][nt][3] - mub[nt]) * rsb[nt] * g4.w + be4.w);
        *(short4*)(&SPb[(nt * 16 + l15) * 200 + cb + cti * 16 + quad * 4]) = sb;
      }
    }
    __syncthreads();               // D: y1n_a, y1n_b ready

    // ---- G2 for both j's; gelu -> HBa/HBb ----
    v4f y2a[3][2], y2b[3][2];
#pragma unroll
    for (int cti = 0; cti < 3; cti++)
#pragma unroll
      for (int nt = 0; nt < 2; nt++) { y2a[cti][nt] = vzero; y2b[cti][nt] = vzero; }
#pragma unroll
    for (int ks = 0; ks < 6; ks++) {
      v8s bha[2], bhb[2];
#pragma unroll
      for (int nt = 0; nt < 2; nt++) {
        bha[nt] = *(const v8s*)(SPa + (nt * 16 + l15) * 200 + ks * 32 + quad * 8);
        bhb[nt] = *(const v8s*)(SPb + (nt * 16 + l15) * 200 + ks * 32 + quad * 8);
      }
#pragma unroll
      for (int cti = 0; cti < 3; cti++) {
        v8s a = *(const v8s*)(W1_bf + (size_t)(cb + cti * 16 + l15) * 192 + ks * 32 + quad * 8);
#pragma unroll
        for (int nt = 0; nt < 2; nt++) {
          y2a[cti][nt] = __builtin_amdgcn_mfma_f32_16x16x32_bf16(a, bha[nt], y2a[cti][nt], 0, 0, 0);
          y2b[cti][nt] = __builtin_amdgcn_mfma_f32_16x16x32_bf16(a, bhb[nt], y2b[cti][nt], 0, 0, 0);
        }
      }
    }
#pragma unroll
    for (int cti = 0; cti < 3; cti++) {
      float4 b14 = *(const float4*)(b1 + cb + cti * 16 + quad * 4);
#pragma unroll
      for (int nt = 0; nt < 2; nt++) {
        short sva[4], svb[4];
#pragma unroll
        for (int r = 0; r < 4; r++) {
          float bb = (r == 0) ? b14.x : (r == 1) ? b14.y : (r == 2) ? b14.z : b14.w;
          float va = y2a[cti][nt][r] + bb;
          float ta = 0.79788456080286536f * (va + 0.044715f * va * va * va);
          float ea = __expf(2.0f * ta);
          sva[r] = f2bf(0.5f * va * (1.0f + (1.0f - 2.0f / (ea + 1.0f))));
          float vb = y2b[cti][nt][r] + bb;
          float tb = 0.79788456080286536f * (vb + 0.044715f * vb * vb * vb);
          float eb = __expf(2.0f * tb);
          svb[r] = f2bf(0.5f * vb * (1.0f + (1.0f - 2.0f / (eb + 1.0f))));
        }
        short4 sa, sb;
        sa.x = sva[0]; sa.y = sva[1]; sa.z = sva[2]; sa.w = sva[3];
        sb.x = svb[0]; sb.y = svb[1]; sb.z = svb[2]; sb.w = svb[3];
        *(short4*)(&HBa[(nt * 16 + l15) * 200 + cb + cti * 16 + quad * 4]) = sa;
        *(short4*)(&HBb[(nt * 16 + l15) * 200 + cb + cti * 16 + quad * 4]) = sb;
      }
    }
    __syncthreads();               // E: h_a, h_b ready; G2 SP reads done

    // ---- G3 for both j's: acc += W2 . h^T (one load -> 4 MFMAs) ----
#pragma unroll
    for (int ks = 0; ks < 6; ks++) {
      v8s bha[2], bhb[2];
#pragma unroll
      for (int nt = 0; nt < 2; nt++) {
        bha[nt] = *(const v8s*)(HBa + (nt * 16 + l15) * 200 + ks * 32 + quad * 8);
        bhb[nt] = *(const v8s*)(HBb + (nt * 16 + l15) * 200 + ks * 32 + quad * 8);
      }
#pragma unroll
      for (int cti = 0; cti < 3; cti++) {
        v8s a = *(const v8s*)(W2_bf + (size_t)(cb + cti * 16 + l15) * 192 + ks * 32 + quad * 8);
#pragma unroll
        for (int nt = 0; nt < 2; nt++) {
          acc[cti][nt] = __builtin_amdgcn_mfma_f32_16x16x32_bf16(a, bha[nt], acc[cti][nt], 0, 0, 0);
          acc[cti][nt] = __builtin_amdgcn_mfma_f32_16x16x32_bf16(a, bhb[nt], acc[cti][nt], 0, 0, 0);
        }
      }
    }
  }

  // ---- epilogue: stage acc/6 to LDS (f32), write full contiguous rows ----
  // SPf: 16 rows x pitch 196 f32 = 12544 B <= 12800 B (SPa).
  float* SPf = (float*)SPa;
#pragma unroll
  for (int pass = 0; pass < 2; pass++) {
    __syncthreads();               // SP/HB reads done (pass 0) / prior pass copy done
#pragma unroll
    for (int cti = 0; cti < 3; cti++) {
      float4 o4;
      o4.x = acc[cti][pass][0] * (1.0f / 6.0f);
      o4.y = acc[cti][pass][1] * (1.0f / 6.0f);
      o4.z = acc[cti][pass][2] * (1.0f / 6.0f);
      o4.w = acc[cti][pass][3] * (1.0f / 6.0f);
      *(float4*)(&SPf[l15 * 196 + cb + cti * 16 + quad * 4]) = o4;
    }
    __syncthreads();
    // 16 rows x 48 float4; both output halves written from one x read
    for (int c = tid; c < 768; c += 256) {
      int r16 = c / 48, col4 = (c - r16 * 48) * 4;
      int row = half * 32 + pass * 16 + r16;
      size_t nrow = (size_t)b * 384 + (size_t)i * 64 + row;
      float4 xv = *(const float4*)(x + nrow * DIM + col4);
      float4 b24 = *(const float4*)(b2 + col4);
      float4 av = *(const float4*)(&SPf[r16 * 196 + col4]);
      float4 o4;
      o4.x = xv.x + av.x + b24.x;
      o4.y = xv.y + av.y + b24.y;
      o4.z = xv.z + av.z + b24.z;
      o4.w = xv.w + av.w + b24.w;
      *(float4*)(out + nrow * 384 + col4) = xv;             // x half bit-exact
      *(float4*)(out + nrow * 384 + 192 + col4) = o4;
    }
  }
}

extern "C" void kernel_launch(void* const* d_in, const int* in_sizes, int n_in,
                              void* d_out, int out_size, void* d_ws, size_t ws_size,
                              hipStream_t stream) {
  (void)in_sizes; (void)n_in; (void)out_size; (void)ws_size;
  const float* x     = (const float*)d_in[0];
  const float* Wqkv  = (const float*)d_in[1];
  const float* Wproj = (const float*)d_in[2];
  const float* bproj = (const float*)d_in[3];
  const float* gamma = (const float*)d_in[4];
  const float* beta  = (const float*)d_in[5];
  const float* W1    = (const float*)d_in[6];
  const float* b1    = (const float*)d_in[7];
  const float* W2    = (const float*)d_in[8];
  const float* b2    = (const float*)d_in[9];
  float* out = (float*)d_out;

  // workspace: weights bf16 + pos f32 + Q/K/Vt bf16
  short* Wqkv_bf  = (short*)d_ws;                 // 576*192
  short* Wproj_bf = Wqkv_bf + 110592;             // 192*384
  short* W1_bf    = Wproj_bf + 73728;             // 192*192
  short* W2_bf    = W1_bf + 36864;                // 192*192
  float* pos_f    = (float*)(W2_bf + 36864);      // 64*192 f32
  short* Qb       = (short*)(pos_f + 12288);      // [b][t][hw][ch]
  short* Kb       = Qb + 9437184;                 // [b][t][hw][ch]
  short* Vtb      = Kb + 9437184;                 // [b][t][ch][hw]

  prep_kernel<<<dim3(264), dim3(256), 0, stream>>>(
      Wqkv, Wproj, W1, W2, Wqkv_bf, Wproj_bf, W1_bf, W2_bf, pos_f);
  qkv_kernel<<<dim3(TT * NB), dim3(256), 0, stream>>>(x, pos_f, Wqkv_bf, Qb, Kb, Vtb);
  fused_all<<<dim3(TT * NB * 2), dim3(256), 0, stream>>>(
      x, Qb, Kb, Vtb, Wproj_bf, W1_bf, W2_bf, bproj, gamma, beta, b1, b2, out);
}

// Round 11
// 567.028 us; speedup vs baseline: 1.1166x; 1.1166x over previous
//
#include <hip/hip_runtime.h>
#include <cmath>

#define TT   6
#define NB   128
#define DIM  192
#define SCALE 0.17677669529663687f

typedef __attribute__((ext_vector_type(8))) short v8s;
typedef __attribute__((ext_vector_type(4))) float v4f;

__device__ __forceinline__ short f2bf(float f) {
  union { float f; unsigned u; } v; v.f = f;
  unsigned r = v.u + 0x7fffu + ((v.u >> 16) & 1u);
  return (short)(r >> 16);
}

// Barrier WITHOUT the vmcnt(0) drain __syncthreads emits. Inter-wave data flow
// in fused_all is LDS-only, so lgkmcnt(0) + s_barrier is sufficient -- and
// prefetched global loads stay in flight across it (the whole point).
__device__ __forceinline__ void ldsbar() {
  __asm__ volatile("s_waitcnt lgkmcnt(0)" ::: "memory");
  __builtin_amdgcn_s_barrier();
  __asm__ volatile("" ::: "memory");
}

// ---- fused prep: bf16 weight conversion + sine position table, one launch ----
__global__ void prep_kernel(const float* __restrict__ Wqkv, const float* __restrict__ Wproj,
                            const float* __restrict__ W1, const float* __restrict__ W2,
                            short* __restrict__ dWqkv, short* __restrict__ dWproj,
                            short* __restrict__ dW1, short* __restrict__ dW2,
                            float* __restrict__ pos) {
  int idx = blockIdx.x * 256 + threadIdx.x;
  const float* src = nullptr; short* dst = nullptr; int off = 0;
  if (idx < 27648)      { src = Wqkv;  dst = dWqkv;  off = idx; }
  else if (idx < 46080) { src = Wproj; dst = dWproj; off = idx - 27648; }
  else if (idx < 55296) { src = W1;    dst = dW1;    off = idx - 46080; }
  else if (idx < 64512) { src = W2;    dst = dW2;    off = idx - 55296; }
  else if (idx < 67584) {
    int p0 = (idx - 64512) * 4;
    float4 r;
    float* rp = (float*)&r;
#pragma unroll
    for (int jj = 0; jj < 4; jj++) {
      int p = p0 + jj;
      int row = p / 192, c = p - row * 192;
      int e  = (c < 96) ? (row >> 3) : (row & 7);
      int cc = (c < 96) ? c : c - 96;
      int m = cc >> 1;
      float embed = (float)(e + 1) * (6.283185307179586f / 8.000001f);
      float dt = powf(10000.0f, (float)m * (1.0f / 48.0f));
      float ang = embed / dt;
      rp[jj] = (cc & 1) ? cosf(ang) : sinf(ang);
    }
    *(float4*)(pos + p0) = r;
    return;
  } else return;
  const float* s = src + off * 4;
  short4 r;
  r.x = f2bf(s[0]); r.y = f2bf(s[1]); r.z = f2bf(s[2]); r.w = f2bf(s[3]);
  *(short4*)(dst + off * 4) = r;
}

// ---- QKV pre-kernel (unchanged, r4-verified XCD swizzle) ----
__global__ __launch_bounds__(256) void qkv_kernel(
    const float* __restrict__ x, const float* __restrict__ pos,
    const short* __restrict__ Wqkv_bf,
    short* __restrict__ Qb, short* __restrict__ Kb, short* __restrict__ Vtb) {
  __shared__ short XP[64 * 200];
  int bid = blockIdx.x;
  int xcd = bid & 7, idx = bid >> 3;
  int bq = idx / TT;
  int b = xcd * 16 + bq, t = idx - bq * TT;
  int tid = threadIdx.x, w = tid >> 6, lane = tid & 63;
  int l15 = lane & 15, quad = lane >> 4;
  const float* xrow = x + (size_t)(b * (TT * 64) + t * 64) * DIM;
  for (int c = tid; c < 64 * 24; c += 256) {
    int row = c / 24, col8 = (c - (c / 24) * 24) * 8;
    const float* xs = xrow + row * DIM + col8;
    const float* pp = pos + row * DIM + col8;
    v8s r8;
#pragma unroll
    for (int jj = 0; jj < 8; jj++) r8[jj] = f2bf(xs[jj] + pp[jj]);
    *(v8s*)(XP + row * 200 + col8) = r8;
  }
  __syncthreads();
  const v4f vzero = {0.f, 0.f, 0.f, 0.f};
  size_t obase = (size_t)(b * TT + t) * 64 * DIM;
#pragma unroll
  for (int cti = 0; cti < 9; cti++) {
    int r0 = w * 144 + cti * 16;
    v4f acc[4] = {vzero, vzero, vzero, vzero};
#pragma unroll
    for (int ks = 0; ks < 6; ks++) {
      v8s a = *(const v8s*)(Wqkv_bf + (size_t)(r0 + l15) * 192 + ks * 32 + quad * 8);
#pragma unroll
      for (int nt = 0; nt < 4; nt++) {
        v8s bb = *(const v8s*)(XP + (nt * 16 + l15) * 200 + ks * 32 + quad * 8);
        acc[nt] = __builtin_amdgcn_mfma_f32_16x16x32_bf16(a, bb, acc[nt], 0, 0, 0);
      }
    }
    int R = r0 + quad * 4;
#pragma unroll
    for (int nt = 0; nt < 4; nt++) {
      int hw = nt * 16 + l15;
      if (R < 192) {
        short4 s;
        s.x = f2bf(acc[nt][0] * SCALE); s.y = f2bf(acc[nt][1] * SCALE);
        s.z = f2bf(acc[nt][2] * SCALE); s.w = f2bf(acc[nt][3] * SCALE);
        *(short4*)(Qb + obase + (size_t)hw * 192 + R) = s;
      } else if (R < 384) {
        short4 s;
        s.x = f2bf(acc[nt][0]); s.y = f2bf(acc[nt][1]);
        s.z = f2bf(acc[nt][2]); s.w = f2bf(acc[nt][3]);
        *(short4*)(Kb + obase + (size_t)hw * 192 + (R - 192)) = s;
      } else {
#pragma unroll
        for (int r = 0; r < 4; r++)
          Vtb[obase + (size_t)(R - 384 + r) * 64 + hw] = f2bf(acc[nt][r]);
      }
    }
  }
}

// register P-transpose (r4/r9-verified): S[4]*inv -> PV B fragments
__device__ __forceinline__ void ptrans(const v4f S[4], float inv,
                                       int srcA, int srcB, bool hiq,
                                       v8s& B0v, v8s& B1v) {
  unsigned pk00, pk01, pk10, pk11, pk20, pk21, pk30, pk31;
  {
    float a0 = S[0][0] * inv, a1 = S[0][1] * inv, a2 = S[0][2] * inv, a3 = S[0][3] * inv;
    __asm__("v_cvt_pk_bf16_f32 %0, %1, %2" : "=v"(pk00) : "v"(a0), "v"(a1));
    __asm__("v_cvt_pk_bf16_f32 %0, %1, %2" : "=v"(pk01) : "v"(a2), "v"(a3));
    float b0 = S[1][0] * inv, b1_ = S[1][1] * inv, b2_ = S[1][2] * inv, b3 = S[1][3] * inv;
    __asm__("v_cvt_pk_bf16_f32 %0, %1, %2" : "=v"(pk10) : "v"(b0), "v"(b1_));
    __asm__("v_cvt_pk_bf16_f32 %0, %1, %2" : "=v"(pk11) : "v"(b2_), "v"(b3));
    float c0 = S[2][0] * inv, c1 = S[2][1] * inv, c2 = S[2][2] * inv, c3 = S[2][3] * inv;
    __asm__("v_cvt_pk_bf16_f32 %0, %1, %2" : "=v"(pk20) : "v"(c0), "v"(c1));
    __asm__("v_cvt_pk_bf16_f32 %0, %1, %2" : "=v"(pk21) : "v"(c2), "v"(c3));
    float d0 = S[3][0] * inv, d1 = S[3][1] * inv, d2 = S[3][2] * inv, d3 = S[3][3] * inv;
    __asm__("v_cvt_pk_bf16_f32 %0, %1, %2" : "=v"(pk30) : "v"(d0), "v"(d1));
    __asm__("v_cvt_pk_bf16_f32 %0, %1, %2" : "=v"(pk31) : "v"(d2), "v"(d3));
  }
  union { unsigned u[4]; v8s v; } B0, B1;
  unsigned ta, tb;
  ta = (unsigned)__shfl((int)pk00, srcA); tb = (unsigned)__shfl((int)pk10, srcA);
  B0.u[0] = hiq ? tb : ta;
  ta = (unsigned)__shfl((int)pk01, srcA); tb = (unsigned)__shfl((int)pk11, srcA);
  B0.u[1] = hiq ? tb : ta;
  ta = (unsigned)__shfl((int)pk00, srcB); tb = (unsigned)__shfl((int)pk10, srcB);
  B0.u[2] = hiq ? tb : ta;
  ta = (unsigned)__shfl((int)pk01, srcB); tb = (unsigned)__shfl((int)pk11, srcB);
  B0.u[3] = hiq ? tb : ta;
  ta = (unsigned)__shfl((int)pk20, srcA); tb = (unsigned)__shfl((int)pk30, srcA);
  B1.u[0] = hiq ? tb : ta;
  ta = (unsigned)__shfl((int)pk21, srcA); tb = (unsigned)__shfl((int)pk31, srcA);
  B1.u[1] = hiq ? tb : ta;
  ta = (unsigned)__shfl((int)pk20, srcB); tb = (unsigned)__shfl((int)pk30, srcB);
  B1.u[2] = hiq ? tb : ta;
  ta = (unsigned)__shfl((int)pk21, srcB); tb = (unsigned)__shfl((int)pk31, srcB);
  B1.u[3] = hiq ? tb : ta;
  B0v = B0.v; B1v = B1.v;
}

// burst-issue one phase's 18 weight fragments (prefetch target array)
__device__ __forceinline__ void issue_w(v8s (&dst)[6][3], const short* __restrict__ Wp,
                                        int rstride, int coff, int rbase, int quad) {
#pragma unroll
  for (int ks = 0; ks < 6; ks++)
#pragma unroll
    for (int cti = 0; cti < 3; cti++)
      dst[ks][cti] = *(const v8s*)(Wp + (size_t)(rbase + cti * 16) * rstride + coff + ks * 32 + quad * 8);
}

// GEMM consume: prefetched weights x LDS activations -> yy accumulators
__device__ __forceinline__ void gemm_consume(const v8s (&wu)[6][3], v4f (&yy)[3][2],
                                             const short* __restrict__ SRC, int l15, int quad) {
#pragma unroll
  for (int ks = 0; ks < 6; ks++) {
    v8s b0 = *(const v8s*)(SRC + (size_t)(l15) * 200 + ks * 32 + quad * 8);
    v8s b1 = *(const v8s*)(SRC + (size_t)(16 + l15) * 200 + ks * 32 + quad * 8);
#pragma unroll
    for (int cti = 0; cti < 3; cti++) {
      yy[cti][0] = __builtin_amdgcn_mfma_f32_16x16x32_bf16(wu[ks][cti], b0, yy[cti][0], 0, 0, 0);
      yy[cti][1] = __builtin_amdgcn_mfma_f32_16x16x32_bf16(wu[ks][cti], b1, yy[cti][1], 0, 0, 0);
    }
  }
}

__device__ __forceinline__ void attn_phase(const short* __restrict__ Kj,
                                           const short* __restrict__ Vj,
                                           const v8s (&qa)[3], short* __restrict__ SP,
                                           int l15, int quad, int hg, int qt,
                                           int srcA, int srcB, bool hiq) {
  const v4f vzero = {0.f, 0.f, 0.f, 0.f};
#pragma unroll
  for (int hh = 0; hh < 3; hh++) {
    int h = hg * 3 + hh;
    v8s kf[4];
#pragma unroll
    for (int cta = 0; cta < 4; cta++)
      kf[cta] = *(const v8s*)(Kj + (size_t)(cta * 16 + l15) * 192 + h * 32 + quad * 8);
    v4f S[4];
#pragma unroll
    for (int cta = 0; cta < 4; cta++)
      S[cta] = __builtin_amdgcn_mfma_f32_16x16x32_bf16(kf[cta], qa[hh], vzero, 0, 0, 0);
    // V loads issued BEFORE the softmax chain -- they land under ~200 VALU cycles
    v8s vf0a = *(const v8s*)(Vj + (size_t)(h * 32 + l15) * 64 + quad * 8);
    v8s vf0b = *(const v8s*)(Vj + (size_t)(h * 32 + l15) * 64 + 32 + quad * 8);
    v8s vf1a = *(const v8s*)(Vj + (size_t)(h * 32 + 16 + l15) * 64 + quad * 8);
    v8s vf1b = *(const v8s*)(Vj + (size_t)(h * 32 + 16 + l15) * 64 + 32 + quad * 8);
    float mx = -1e30f;
#pragma unroll
    for (int cta = 0; cta < 4; cta++)
#pragma unroll
      for (int r = 0; r < 4; r++) mx = fmaxf(mx, S[cta][r]);
    mx = fmaxf(mx, __shfl_xor(mx, 16, 64));
    mx = fmaxf(mx, __shfl_xor(mx, 32, 64));
    float sum = 0.f;
#pragma unroll
    for (int cta = 0; cta < 4; cta++)
#pragma unroll
      for (int r = 0; r < 4; r++) {
        float e = __expf(S[cta][r] - mx);
        S[cta][r] = e; sum += e;
      }
    sum += __shfl_xor(sum, 16, 64);
    sum += __shfl_xor(sum, 32, 64);
    float inv = 1.0f / sum;
    v8s B0, B1;
    ptrans(S, inv, srcA, srcB, hiq, B0, B1);
    v4f o0 = __builtin_amdgcn_mfma_f32_16x16x32_bf16(vf0a, B0, vzero, 0, 0, 0);
    o0 = __builtin_amdgcn_mfma_f32_16x16x32_bf16(vf0b, B1, o0, 0, 0, 0);
    short4 s0;
    s0.x = f2bf(o0[0]); s0.y = f2bf(o0[1]); s0.z = f2bf(o0[2]); s0.w = f2bf(o0[3]);
    *(short4*)(&SP[(qt * 16 + l15) * 200 + h * 32 + quad * 4]) = s0;
    v4f o1 = __builtin_amdgcn_mfma_f32_16x16x32_bf16(vf1a, B0, vzero, 0, 0, 0);
    o1 = __builtin_amdgcn_mfma_f32_16x16x32_bf16(vf1b, B1, o1, 0, 0, 0);
    short4 s1;
    s1.x = f2bf(o1[0]); s1.y = f2bf(o1[1]); s1.z = f2bf(o1[2]); s1.w = f2bf(o1[3]);
    *(short4*)(&SP[(qt * 16 + l15) * 200 + h * 32 + 16 + quad * 4]) = s1;
  }
}

__device__ __forceinline__ void ln_reduce_store(v4f (&y1)[3][2], const float* __restrict__ bproj,
                                                float (*LNp)[4][2], int cb, int l15, int quad, int wc) {
#pragma unroll
  for (int cti = 0; cti < 3; cti++) {
    float4 bp4 = *(const float4*)(bproj + cb + cti * 16 + quad * 4);
#pragma unroll
    for (int nt = 0; nt < 2; nt++) {
      y1[cti][nt][0] += bp4.x; y1[cti][nt][1] += bp4.y;
      y1[cti][nt][2] += bp4.z; y1[cti][nt][3] += bp4.w;
    }
  }
#pragma unroll
  for (int nt = 0; nt < 2; nt++) {
    float s1 = 0.f, s2 = 0.f;
#pragma unroll
    for (int cti = 0; cti < 3; cti++)
#pragma unroll
      for (int r = 0; r < 4; r++) { float v = y1[cti][nt][r]; s1 += v; s2 += v * v; }
    s1 += __shfl_xor(s1, 16, 64); s2 += __shfl_xor(s2, 16, 64);
    s1 += __shfl_xor(s1, 32, 64); s2 += __shfl_xor(s2, 32, 64);
    if (quad == 0) { LNp[nt * 16 + l15][wc][0] = s1; LNp[nt * 16 + l15][wc][1] = s2; }
  }
}

__device__ __forceinline__ void ln_normalize_store(const v4f (&y1)[3][2],
                                                   const float* __restrict__ gamma,
                                                   const float* __restrict__ beta,
                                                   const float (*LNp)[4][2],
                                                   short* __restrict__ SP,
                                                   int cb, int l15, int quad) {
  float mu[2], rs[2];
#pragma unroll
  for (int nt = 0; nt < 2; nt++) {
    int row = nt * 16 + l15;
    float s1 = 0.f, s2 = 0.f;
#pragma unroll
    for (int ww = 0; ww < 4; ww++) { s1 += LNp[row][ww][0]; s2 += LNp[row][ww][1]; }
    float m = s1 * (1.0f / 192.0f);
    mu[nt] = m; rs[nt] = rsqrtf(s2 * (1.0f / 192.0f) - m * m + 1e-5f);
  }
#pragma unroll
  for (int cti = 0; cti < 3; cti++) {
    float4 g4 = *(const float4*)(gamma + cb + cti * 16 + quad * 4);
    float4 be4 = *(const float4*)(beta + cb + cti * 16 + quad * 4);
#pragma unroll
    for (int nt = 0; nt < 2; nt++) {
      short4 s;
      s.x = f2bf((y1[cti][nt][0] - mu[nt]) * rs[nt] * g4.x + be4.x);
      s.y = f2bf((y1[cti][nt][1] - mu[nt]) * rs[nt] * g4.y + be4.y);
      s.z = f2bf((y1[cti][nt][2] - mu[nt]) * rs[nt] * g4.z + be4.z);
      s.w = f2bf((y1[cti][nt][3] - mu[nt]) * rs[nt] * g4.w + be4.w);
      *(short4*)(&SP[(nt * 16 + l15) * 200 + cb + cti * 16 + quad * 4]) = s;
    }
  }
}

__device__ __forceinline__ void gelu_store(const v4f (&y2)[3][2], const float* __restrict__ b1,
                                           short* __restrict__ HB, int cb, int l15, int quad) {
#pragma unroll
  for (int cti = 0; cti < 3; cti++) {
    float4 b14 = *(const float4*)(b1 + cb + cti * 16 + quad * 4);
#pragma unroll
    for (int nt = 0; nt < 2; nt++) {
      float vv[4] = {y2[cti][nt][0] + b14.x, y2[cti][nt][1] + b14.y,
                     y2[cti][nt][2] + b14.z, y2[cti][nt][3] + b14.w};
      short sv[4];
#pragma unroll
      for (int r = 0; r < 4; r++) {
        float v = vv[r];
        float t = 0.79788456080286536f * (v + 0.044715f * v * v * v);
        float e = __expf(2.0f * t);
        float th = 1.0f - 2.0f / (e + 1.0f);
        sv[r] = f2bf(0.5f * v * (1.0f + th));
      }
      short4 s;
      s.x = sv[0]; s.y = sv[1]; s.z = sv[2]; s.w = sv[3];
      *(short4*)(&HB[(nt * 16 + l15) * 200 + cb + cti * 16 + quad * 4]) = s;
    }
  }
}

// One j-iteration; WU holds this j's Wproj fragments on entry. Issues W1->WN
// during G1, W2->WU during G2, next-j Wproj->WN during G3 (software pipeline).
#define JBODY(WU, WN, JV)                                                      \
  {                                                                            \
    int j = (JV);                                                              \
    ldsbar(); /* A: SP free for o (prior G2 reads done) */                     \
    attn_phase(Kb + (size_t)(b * TT + j) * 64 * DIM,                           \
               Vtb + (size_t)(b * TT + j) * 64 * DIM,                          \
               qa, SP, l15, quad, hg, qt, srcA, srcB, hiq);                    \
    ldsbar(); /* B: o ready */                                                 \
    v4f y1[3][2];                                                              \
    _Pragma("unroll") for (int c_ = 0; c_ < 3; c_++)                           \
      _Pragma("unroll") for (int n_ = 0; n_ < 2; n_++) y1[c_][n_] = y1x[c_][n_]; \
    gemm_consume(WU, y1, SP, l15, quad);                                       \
    issue_w(WN, W1_bf, 192, 0, cb + l15, quad);                                \
    ln_reduce_store(y1, bproj, LNp, cb, l15, quad, wc);                        \
    ldsbar(); /* C: partials visible; G1 SP reads done */                      \
    ln_normalize_store(y1, gamma, beta, LNp, SP, cb, l15, quad);               \
    ldsbar(); /* D: y1n ready */                                               \
    v4f y2[3][2];                                                              \
    _Pragma("unroll") for (int c_ = 0; c_ < 3; c_++)                           \
      _Pragma("unroll") for (int n_ = 0; n_ < 2; n_++) y2[c_][n_] = vzero;     \
    gemm_consume(WN, y2, SP, l15, quad);                                       \
    issue_w(WU, W2_bf, 192, 0, cb + l15, quad);                                \
    gelu_store(y2, b1, HB, cb, l15, quad);                                     \
    ldsbar(); /* E: h ready; G2 SP reads done */                               \
    gemm_consume(WU, acc, HB, l15, quad);                                      \
    if (j < TT - 1) issue_w(WN, Wproj_bf, 384, 0, cb + l15, quad);             \
  }

// ---- main fused kernel: one block per (i,b,half), 256 threads (4 waves), 32 hw rows.
// r9 base + (a) non-draining lgkm-only barriers, (b) one-phase-ahead weight
// prefetch into alternating register arrays wA/wB. Numerically identical to r9.
// __launch_bounds__(256,2): 256-reg cap so the 72-VGPR prefetch windows fit.
__global__ __launch_bounds__(256, 2) void fused_all(
    const float* __restrict__ x,
    const short* __restrict__ Qb, const short* __restrict__ Kb,
    const short* __restrict__ Vtb,
    const short* __restrict__ Wproj_bf, const short* __restrict__ W1_bf,
    const short* __restrict__ W2_bf,
    const float* __restrict__ bproj, const float* __restrict__ gamma,
    const float* __restrict__ beta, const float* __restrict__ b1,
    const float* __restrict__ b2,
    float* __restrict__ out) {
  __shared__ short SP[32 * 200];     // Xi staging / o / y1n; f32 acc staging in epilogue
  __shared__ short HB[32 * 200];     // gelu output h
  __shared__ float LNp[32][4][2];    // LN partials: [row][wc][s1,s2]

  int bid = blockIdx.x;
  int xcd = bid & 7, idx = bid >> 3;     // 192 per XCD
  int bq = idx / 12;
  int rem = idx - bq * 12;
  int i = rem >> 1, half = rem & 1;
  int b = xcd * 16 + bq;

  int tid = threadIdx.x, w = tid >> 6, lane = tid & 63;
  int l15 = lane & 15, quad = lane >> 4;
  int wc = w;                        // GEMM channel slice
  int qt = w & 1, hg = w >> 1;       // attention: q-tile, head-group
  int cb = wc * 48;
  const v4f vzero = {0.f, 0.f, 0.f, 0.f};

  // ---- stage Xi (x.view rows, this half) as bf16 into SP ----
  const float* xi = x + (size_t)((i * NB + b) * 64 + half * 32) * DIM;
  for (int c = tid; c < 32 * 24; c += 256) {
    int row = c / 24, col8 = (c - (c / 24) * 24) * 8;
    const float* xs = xi + row * DIM + col8;
    v8s r8;
#pragma unroll
    for (int jj = 0; jj < 8; jj++) r8[jj] = f2bf(xs[jj]);
    *(v8s*)(SP + row * 200 + col8) = r8;
  }

  // ---- hoist Q fragments (j-invariant) ----
  const short* Qi = Qb + (size_t)(b * TT + i) * 64 * DIM;
  v8s qa[3];
#pragma unroll
  for (int hh = 0; hh < 3; hh++)
    qa[hh] = *(const v8s*)(Qi + (size_t)(half * 32 + qt * 16 + l15) * 192 + (hg * 3 + hh) * 32 + quad * 8);

  v4f acc[3][2];
#pragma unroll
  for (int cti = 0; cti < 3; cti++)
#pragma unroll
    for (int nt = 0; nt < 2; nt++) acc[cti][nt] = vzero;

  ldsbar();                          // Xi staged

  // ---- y1x = Wproj[:,192:384] . Xi^T (j-invariant, registers) ----
  v4f y1x[3][2];
#pragma unroll
  for (int cti = 0; cti < 3; cti++)
#pragma unroll
    for (int nt = 0; nt < 2; nt++) y1x[cti][nt] = vzero;
#pragma unroll
  for (int ks = 0; ks < 6; ks++) {
    v8s bxi0 = *(const v8s*)(SP + (size_t)(l15) * 200 + ks * 32 + quad * 8);
    v8s bxi1 = *(const v8s*)(SP + (size_t)(16 + l15) * 200 + ks * 32 + quad * 8);
#pragma unroll
    for (int cti = 0; cti < 3; cti++) {
      v8s a = *(const v8s*)(Wproj_bf + (size_t)(cb + cti * 16 + l15) * 384 + 192 + ks * 32 + quad * 8);
      y1x[cti][0] = __builtin_amdgcn_mfma_f32_16x16x32_bf16(a, bxi0, y1x[cti][0], 0, 0, 0);
      y1x[cti][1] = __builtin_amdgcn_mfma_f32_16x16x32_bf16(a, bxi1, y1x[cti][1], 0, 0, 0);
    }
  }

  int srcA = l15 + ((lane & 16) << 1);   // l15 + 32*(quad&1)
  int srcB = srcA + 16;
  bool hiq = (lane & 32) != 0;           // quad >= 2

  // ---- software pipeline: prologue issues j=0's Wproj fragments ----
  v8s wA[6][3], wB[6][3];
  issue_w(wA, Wproj_bf, 384, 0, cb + l15, quad);

  for (int jp = 0; jp < 3; jp++) {
    JBODY(wA, wB, jp * 2);       // G1:wA(Wproj) G2:wB(W1) G3:wA(W2); next Wproj->wB
    JBODY(wB, wA, jp * 2 + 1);   // G1:wB(Wproj) G2:wA(W1) G3:wB(W2); next Wproj->wA
  }

  // ---- epilogue: stage acc/6 to LDS (f32), write full contiguous rows ----
  float* SPf = (float*)SP;
#pragma unroll
  for (int pass = 0; pass < 2; pass++) {
    ldsbar();                      // SP/HB reads done (pass 0) / prior pass copy done
#pragma unroll
    for (int cti = 0; cti < 3; cti++) {
      float4 o4;
      o4.x = acc[cti][pass][0] * (1.0f / 6.0f);
      o4.y = acc[cti][pass][1] * (1.0f / 6.0f);
      o4.z = acc[cti][pass][2] * (1.0f / 6.0f);
      o4.w = acc[cti][pass][3] * (1.0f / 6.0f);
      *(float4*)(&SPf[l15 * 196 + cb + cti * 16 + quad * 4]) = o4;
    }
    ldsbar();
    for (int c = tid; c < 768; c += 256) {
      int r16 = c / 48, col4 = (c - r16 * 48) * 4;
      int row = half * 32 + pass * 16 + r16;
      size_t nrow = (size_t)b * 384 + (size_t)i * 64 + row;
      float4 xv = *(const float4*)(x + nrow * DIM + col4);
      float4 b24 = *(const float4*)(b2 + col4);
      float4 av = *(const float4*)(&SPf[r16 * 196 + col4]);
      float4 o4;
      o4.x = xv.x + av.x + b24.x;
      o4.y = xv.y + av.y + b24.y;
      o4.z = xv.z + av.z + b24.z;
      o4.w = xv.w + av.w + b24.w;
      *(float4*)(out + nrow * 384 + col4) = xv;             // x half bit-exact
      *(float4*)(out + nrow * 384 + 192 + col4) = o4;
    }
  }
}

extern "C" void kernel_launch(void* const* d_in, const int* in_sizes, int n_in,
                              void* d_out, int out_size, void* d_ws, size_t ws_size,
                              hipStream_t stream) {
  (void)in_sizes; (void)n_in; (void)out_size; (void)ws_size;
  const float* x     = (const float*)d_in[0];
  const float* Wqkv  = (const float*)d_in[1];
  const float* Wproj = (const float*)d_in[2];
  const float* bproj = (const float*)d_in[3];
  const float* gamma = (const float*)d_in[4];
  const float* beta  = (const float*)d_in[5];
  const float* W1    = (const float*)d_in[6];
  const float* b1    = (const float*)d_in[7];
  const float* W2    = (const float*)d_in[8];
  const float* b2    = (const float*)d_in[9];
  float* out = (float*)d_out;

  // workspace: weights bf16 + pos f32 + Q/K/Vt bf16
  short* Wqkv_bf  = (short*)d_ws;                 // 576*192
  short* Wproj_bf = Wqkv_bf + 110592;             // 192*384
  short* W1_bf    = Wproj_bf + 73728;             // 192*192
  short* W2_bf    = W1_bf + 36864;                // 192*192
  float* pos_f    = (float*)(W2_bf + 36864);      // 64*192 f32
  short* Qb       = (short*)(pos_f + 12288);      // [b][t][hw][ch]
  short* Kb       = Qb + 9437184;                 // [b][t][hw][ch]
  short* Vtb      = Kb + 9437184;                 // [b][t][ch][hw]

  prep_kernel<<<dim3(264), dim3(256), 0, stream>>>(
      Wqkv, Wproj, W1, W2, Wqkv_bf, Wproj_bf, W1_bf, W2_bf, pos_f);
  qkv_kernel<<<dim3(TT * NB), dim3(256), 0, stream>>>(x, pos_f, Wqkv_bf, Qb, Kb, Vtb);
  fused_all<<<dim3(TT * NB * 2), dim3(256), 0, stream>>>(
      x, Qb, Kb, Vtb, Wproj_bf, W1_bf, W2_bf, bproj, gamma, beta, b1, b2, out);
}